// Round 6
// baseline (244.036 us; speedup 1.0000x reference)
//
#include <hip/hip_runtime.h>
#include <cstdint>
#include <cstddef>

// GlobalAttention (Luong 'general'): q = src@W^T ; x = q@MB^T ; softmax(mask) ; c = P@MB
// Outputs: d_out = [ c (8*1024*256) | align_vectors (8*1024*4096) ] fp32.
// Pipeline: k_qproj -> k_fstats (online stats, no x store) -> k_stats
//        -> k_pvfused v2 (recompute x, p once, PV) -> k_csum
//
// R6: R5's pvfused collapsed (167 us) from exposed staging latency: per-4-load
// pack+write serialization, 72KB LDS -> 2 blocks/CU, 8-16-way VT write conflicts.
// v2: batched reg staging issued BEFORE the barrier (hides under prev PV),
// s-step 32 / 35KB LDS / 3 blocks/CU, VT re-laid as [128][64] 128B rows (2-way
// max), Ps padded to 80B rows (conflict-free), kc=4.

typedef _Float16 f16;
typedef _Float16 half8 __attribute__((ext_vector_type(8)));
typedef _Float16 half4v __attribute__((ext_vector_type(4)));
typedef float f32x4 __attribute__((ext_vector_type(4)));

#define MFMA16(a, b, c) __builtin_amdgcn_mfma_f32_16x16x32_f16((a), (b), (c), 0, 0, 0)

static constexpr int NBATCH = 8;
static constexpr int NT = 1024;   // TGT
static constexpr int NS = 4096;   // SRC
static constexpr int ND = 256;    // SDIM == TDIM
static constexpr float NEGBIG = -3.0e38f;

// XOR swizzle within an LDS row (flips 16B-slot bits; b64/b128-safe)
__device__ __forceinline__ int swz(int row, int byteInRow) {
  return byteInRow ^ ((row & 7) << 4);
}

// ---------------- K1: q16 = source @ W^T (fp16 out) ----------------
__global__ __launch_bounds__(256) void k_qproj(const float* __restrict__ src,
                                               const float* __restrict__ W,
                                               f16* __restrict__ q16) {
  __shared__ __align__(16) f16 As[64 * 64];
  __shared__ __align__(16) f16 Bs[256 * 64];
  const int tid = threadIdx.x;
  const int w = tid >> 6, l = tid & 63;
  const int wt = w >> 1, wn = w & 1;
  const int q = l >> 4, lc = l & 15;
  const int t0 = blockIdx.x * 64;

  f32x4 acc[2][8];
#pragma unroll
  for (int i = 0; i < 2; ++i)
#pragma unroll
    for (int j = 0; j < 8; ++j) acc[i][j] = (f32x4){0.f, 0.f, 0.f, 0.f};

  for (int k0 = 0; k0 < 256; k0 += 64) {
    __syncthreads();
    {
      const int r = tid >> 2, c2 = (tid & 3) * 2;
      const float* g = src + (size_t)(t0 + r) * 256 + k0 + c2 * 8;
      float4 f0 = ((const float4*)g)[0], f1 = ((const float4*)g)[1];
      float4 f2 = ((const float4*)g)[2], f3 = ((const float4*)g)[3];
      half8 h0 = {(f16)f0.x, (f16)f0.y, (f16)f0.z, (f16)f0.w,
                  (f16)f1.x, (f16)f1.y, (f16)f1.z, (f16)f1.w};
      half8 h1 = {(f16)f2.x, (f16)f2.y, (f16)f2.z, (f16)f2.w,
                  (f16)f3.x, (f16)f3.y, (f16)f3.z, (f16)f3.w};
      *(half8*)((char*)As + r * 128 + swz(r, c2 * 16)) = h0;
      *(half8*)((char*)As + r * 128 + swz(r, c2 * 16 + 16)) = h1;
    }
    {
      const int n = tid;
      const float* g = W + (size_t)n * 256 + k0;
#pragma unroll
      for (int c = 0; c < 8; ++c) {
        float4 f0 = ((const float4*)(g + c * 8))[0];
        float4 f1 = ((const float4*)(g + c * 8))[1];
        half8 h = {(f16)f0.x, (f16)f0.y, (f16)f0.z, (f16)f0.w,
                   (f16)f1.x, (f16)f1.y, (f16)f1.z, (f16)f1.w};
        *(half8*)((char*)Bs + n * 128 + swz(n, c * 16)) = h;
      }
    }
    __syncthreads();
    half8 a[2][2], bb[8][2];
#pragma unroll
    for (int mb = 0; mb < 2; ++mb)
#pragma unroll
      for (int kf = 0; kf < 2; ++kf) {
        const int r = wt * 32 + mb * 16 + lc;
        a[mb][kf] = *(const half8*)((const char*)As + r * 128 + swz(r, kf * 64 + q * 16));
      }
#pragma unroll
    for (int nb = 0; nb < 8; ++nb)
#pragma unroll
      for (int kf = 0; kf < 2; ++kf) {
        const int r = wn * 128 + nb * 16 + lc;
        bb[nb][kf] = *(const half8*)((const char*)Bs + r * 128 + swz(r, kf * 64 + q * 16));
      }
#pragma unroll
    for (int kf = 0; kf < 2; ++kf)
#pragma unroll
      for (int mb = 0; mb < 2; ++mb)
#pragma unroll
        for (int nb = 0; nb < 8; ++nb)
          acc[mb][nb] = MFMA16(a[mb][kf], bb[nb][kf], acc[mb][nb]);
  }
#pragma unroll
  for (int mb = 0; mb < 2; ++mb)
#pragma unroll
    for (int nb = 0; nb < 8; ++nb)
#pragma unroll
      for (int j = 0; j < 4; ++j) {
        const int t = t0 + wt * 32 + mb * 16 + q * 4 + j;
        const int n = wn * 128 + nb * 16 + lc;
        q16[(size_t)t * 256 + n] = (f16)acc[mb][nb][j];
      }
}

// ---------------- K2: flash stats — x via MFMA, online (m, sumexp), NO x store ----
__global__ __launch_bounds__(256, 3) void k_fstats(const float* __restrict__ mbank,
                                                   const f16* __restrict__ q16,
                                                   const int* __restrict__ mask,
                                                   float* __restrict__ pstats) {
  __shared__ __align__(16) f16 Bs[64 * 256];  // [s][d] f16, 512B rows, swizzled (32 KB)
  const int tid = threadIdx.x;
  const int w = tid >> 6, l = tid & 63;
  const int q = l >> 4, lc = l & 15;
  const int bid = blockIdx.x;
  const int b = bid & 7;
  const int sc = (bid >> 3) & 7;
  const int tt = bid >> 6;
  const int t0 = tt * 128;
  const int s0 = sc * 512;

  half8 aq[2][8];
#pragma unroll
  for (int mb = 0; mb < 2; ++mb)
#pragma unroll
    for (int kf = 0; kf < 8; ++kf)
      aq[mb][kf] = *(const half8*)(q16 +
          (size_t)(b * NT + t0 + w * 32 + mb * 16 + lc) * 256 + kf * 32 + q * 8);

  float mrun[8], lrun[8];
#pragma unroll
  for (int i = 0; i < 8; ++i) { mrun[i] = NEGBIG; lrun[i] = 0.f; }

  const int br = tid >> 2;
  const int cb = (tid & 3) * 64;
  for (int st = 0; st < 8; ++st) {
    const int sb = s0 + st * 64;
    __syncthreads();
    {
      const float4* g = (const float4*)(mbank + ((size_t)b * NS + sb + br) * ND + cb);
#pragma unroll
      for (int i = 0; i < 8; ++i) {
        float4 f0 = g[2 * i], f1 = g[2 * i + 1];
        half8 h = {(f16)f0.x, (f16)f0.y, (f16)f0.z, (f16)f0.w,
                   (f16)f1.x, (f16)f1.y, (f16)f1.z, (f16)f1.w};
        *(half8*)((char*)Bs + br * 512 + swz(br, cb * 2 + i * 16)) = h;
      }
    }
    __syncthreads();
    f32x4 xacc[2][4];
#pragma unroll
    for (int i = 0; i < 2; ++i)
#pragma unroll
      for (int j = 0; j < 4; ++j) xacc[i][j] = (f32x4){0.f, 0.f, 0.f, 0.f};
#pragma unroll
    for (int kf = 0; kf < 8; ++kf)
#pragma unroll
      for (int nb = 0; nb < 4; ++nb) {
        const int rs = nb * 16 + lc;
        half8 bb = *(const half8*)((const char*)Bs + rs * 512 + swz(rs, kf * 64 + q * 16));
#pragma unroll
        for (int mb = 0; mb < 2; ++mb)
          xacc[mb][nb] = MFMA16(aq[mb][kf], bb, xacc[mb][nb]);
      }
    bool keep[4];
#pragma unroll
    for (int nb = 0; nb < 4; ++nb)
      keep[nb] = mask[(size_t)b * NS + sb + nb * 16 + lc] != 0;
#pragma unroll
    for (int mb = 0; mb < 2; ++mb)
#pragma unroll
      for (int j = 0; j < 4; ++j) {
        float v[4];
#pragma unroll
        for (int nb = 0; nb < 4; ++nb) v[nb] = keep[nb] ? xacc[mb][nb][j] : NEGBIG;
        float m2 = fmaxf(fmaxf(v[0], v[1]), fmaxf(v[2], v[3]));
#pragma unroll
        for (int d = 1; d < 16; d <<= 1) m2 = fmaxf(m2, __shfl_xor(m2, d));
        float s2 = 0.f;
#pragma unroll
        for (int nb = 0; nb < 4; ++nb) s2 += __expf(v[nb] - m2);
#pragma unroll
        for (int d = 1; d < 16; d <<= 1) s2 += __shfl_xor(s2, d);
        const int idx = mb * 4 + j;
        const float mn = fmaxf(mrun[idx], m2);
        lrun[idx] = lrun[idx] * __expf(mrun[idx] - mn) + s2 * __expf(m2 - mn);
        mrun[idx] = mn;
      }
  }
  if (lc == 0) {
#pragma unroll
    for (int mb = 0; mb < 2; ++mb)
#pragma unroll
      for (int j = 0; j < 4; ++j) {
        const int row = t0 + w * 32 + mb * 16 + q * 4 + j;
        const int idx = mb * 4 + j;
        pstats[(((size_t)b * NT + row) * 8 + sc) * 2 + 0] = mrun[idx];
        pstats[(((size_t)b * NT + row) * 8 + sc) * 2 + 1] = lrun[idx];
      }
  }
}

// ---------------- K3: reduce 8 chunk partials -> m, 1/l per row ----------------
__global__ __launch_bounds__(256) void k_stats(const float* __restrict__ pstats,
                                               float* __restrict__ sm,
                                               float* __restrict__ slinv) {
  const int r = blockIdx.x * 256 + threadIdx.x;  // 0..8191
  const float4* p = (const float4*)(pstats + (size_t)r * 16);
  float4 v[4];
  float mm = NEGBIG;
#pragma unroll
  for (int i = 0; i < 4; ++i) {
    v[i] = p[i];
    mm = fmaxf(mm, fmaxf(v[i].x, v[i].z));
  }
  float ll = 0.f;
#pragma unroll
  for (int i = 0; i < 4; ++i)
    ll += v[i].y * __expf(v[i].x - mm) + v[i].w * __expf(v[i].z - mm);
  sm[r] = mm;
  slinv[r] = (ll > 0.f) ? (1.f / ll) : 0.f;
}

// ---------------- K4 v2: recompute x, p once -> align ; partial c = P@V ----------
// flat grid 1024: b = bid&7, kc = (bid>>3)&3 (1024-s chunk), tt = bid>>5 (32t).
// block 256 = 4 waves: tg = w>>1 (16t) x wd = w&1 (128d). 32 steps of 32 s.
// LDS: Bs [32s][256d] f16 swizzled (16K); VT2 [128][64] f16: (d,s) at row d>>1,
// col s+32*(d&1), swizzled 128B rows (16K); Ps [32t][40] f16 pad-80B rows (2.5K).
__global__ __launch_bounds__(256, 3) void k_pvfused(const float* __restrict__ mbank,
                                                    const f16* __restrict__ q16,
                                                    const int* __restrict__ mask,
                                                    const float* __restrict__ sm,
                                                    const float* __restrict__ slinv,
                                                    float* __restrict__ alignv,
                                                    f16* __restrict__ pc) {
  __shared__ __align__(16) f16 Bs[32 * 256];
  __shared__ __align__(16) f16 VT2[128 * 64];
  __shared__ __align__(16) f16 Ps[32 * 40];
  const int tid = threadIdx.x;
  const int w = tid >> 6, l = tid & 63;
  const int tg = w >> 1, wd = w & 1;
  const int q = l >> 4, lc = l & 15;
  const int bid = blockIdx.x;
  const int b = bid & 7;
  const int kc = (bid >> 3) & 3;
  const int tt = bid >> 5;
  const int t0 = tt * 32;
  const int s0 = kc * 1024;

  // per-wave A fragments (16 t-rows), loaded once
  half8 aq[8];
#pragma unroll
  for (int kf = 0; kf < 8; ++kf)
    aq[kf] = *(const half8*)(q16 +
        (size_t)(b * NT + t0 + tg * 16 + lc) * 256 + kf * 32 + q * 8);

  float mrowv[4], linvv[4];
#pragma unroll
  for (int j = 0; j < 4; ++j) {
    const size_t rg = (size_t)b * NT + t0 + tg * 16 + q * 4 + j;
    mrowv[j] = sm[rg];
    linvv[j] = slinv[rg];
  }

  f32x4 acc[8];
#pragma unroll
  for (int i = 0; i < 8; ++i) acc[i] = (f32x4){0.f, 0.f, 0.f, 0.f};

  // staging ownership
  const int brow = tid >> 3, bcol = (tid & 7) * 4;  // Bs: row, f32 col (+i*32)
  const int dver = tid;                              // VT2: this thread's d row
  const int vrow = dver >> 1;                        // VT2 LDS row
  const int vhalf = (dver & 1) * 64;                 // byte offset of s-half

  for (int st = 0; st < 32; ++st) {
    const int sb = s0 + st * 32;
    const float* gB = mbank + ((size_t)b * NS + sb + brow) * ND;
    const float* gV = mbank + ((size_t)b * NS + sb) * ND + dver;

    // --- batched stage loads (issued before barrier: hide under prev PV) ---
    float4 rb[8];
#pragma unroll
    for (int i = 0; i < 8; ++i) rb[i] = *(const float4*)(gB + bcol + i * 32);
    float rvA[16];
#pragma unroll
    for (int s = 0; s < 16; ++s) rvA[s] = gV[(size_t)s * ND];

    __syncthreads();  // prev PV done reading LDS

    // Bs writes (frees rb)
#pragma unroll
    for (int i = 0; i < 8; ++i) {
      half4v h = {(f16)rb[i].x, (f16)rb[i].y, (f16)rb[i].z, (f16)rb[i].w};
      *(half4v*)((char*)Bs + brow * 512 + swz(brow, (bcol + i * 32) * 2)) = h;
    }
    // second VT batch
    float rvB[16];
#pragma unroll
    for (int s = 0; s < 16; ++s) rvB[s] = gV[(size_t)(16 + s) * ND];
    // VT writes
#pragma unroll
    for (int i = 0; i < 2; ++i) {
      half8 h = {(f16)rvA[i * 8 + 0], (f16)rvA[i * 8 + 1], (f16)rvA[i * 8 + 2],
                 (f16)rvA[i * 8 + 3], (f16)rvA[i * 8 + 4], (f16)rvA[i * 8 + 5],
                 (f16)rvA[i * 8 + 6], (f16)rvA[i * 8 + 7]};
      *(half8*)((char*)VT2 + vrow * 128 + swz(vrow, vhalf + i * 16)) = h;
    }
#pragma unroll
    for (int i = 0; i < 2; ++i) {
      half8 h = {(f16)rvB[i * 8 + 0], (f16)rvB[i * 8 + 1], (f16)rvB[i * 8 + 2],
                 (f16)rvB[i * 8 + 3], (f16)rvB[i * 8 + 4], (f16)rvB[i * 8 + 5],
                 (f16)rvB[i * 8 + 6], (f16)rvB[i * 8 + 7]};
      *(half8*)((char*)VT2 + vrow * 128 + swz(vrow, vhalf + 32 + i * 16)) = h;
    }
    __syncthreads();  // LDS ready

    // --- QK: x = q @ MB^T for this wave's 16t x 32s ---
    f32x4 xacc[2];
    xacc[0] = (f32x4){0.f, 0.f, 0.f, 0.f};
    xacc[1] = (f32x4){0.f, 0.f, 0.f, 0.f};
#pragma unroll
    for (int kf = 0; kf < 8; ++kf)
#pragma unroll
      for (int nb = 0; nb < 2; ++nb) {
        const int rs = nb * 16 + lc;
        half8 bb = *(const half8*)((const char*)Bs + rs * 512 + swz(rs, kf * 64 + q * 16));
        xacc[nb] = MFMA16(aq[kf], bb, xacc[nb]);
      }
    // mask -> p -> store global + Ps
    bool keepn[2];
#pragma unroll
    for (int nb = 0; nb < 2; ++nb)
      keepn[nb] = mask[(size_t)b * NS + sb + nb * 16 + lc] != 0;
#pragma unroll
    for (int nb = 0; nb < 2; ++nb)
#pragma unroll
      for (int j = 0; j < 4; ++j) {
        const float pj = keepn[nb] ? __expf(xacc[nb][j] - mrowv[j]) * linvv[j] : 0.f;
        const int tl = tg * 16 + q * 4 + j;
        const int sl = nb * 16 + lc;
        alignv[((size_t)b * NT + t0 + tl) * NS + sb + sl] = pj;
        *(f16*)((char*)Ps + tl * 80 + sl * 2) = (f16)pj;
      }
    __syncthreads();  // Ps ready

    // --- PV: c += P @ V ---
    const half8 apv = *(const half8*)((const char*)Ps + (tg * 16 + lc) * 80 + q * 16);
#pragma unroll
    for (int nb = 0; nb < 8; ++nb) {
      const int d = wd * 128 + nb * 16 + lc;
      const int vr = d >> 1;
      half8 bb = *(const half8*)((const char*)VT2 + vr * 128 +
                                 swz(vr, (d & 1) * 64 + q * 16));
      acc[nb] = MFMA16(apv, bb, acc[nb]);
    }
  }

#pragma unroll
  for (int nb = 0; nb < 8; ++nb)
#pragma unroll
    for (int j = 0; j < 4; ++j) {
      const int t = t0 + tg * 16 + q * 4 + j;
      const int d = wd * 128 + nb * 16 + lc;
      pc[(size_t)kc * ((size_t)NBATCH * NT * ND) + ((size_t)b * NT + t) * ND + d] =
          (f16)acc[nb][j];
    }
}

// ---------------- K5: c = sum of 4 fp16 split-K partials ----------------
__global__ __launch_bounds__(256) void k_csum(const f16* __restrict__ pc,
                                              float* __restrict__ outc) {
  const size_t i8 = ((size_t)blockIdx.x * 256 + threadIdx.x) * 8;
  const size_t STRIDE = (size_t)NBATCH * NT * ND;  // 2097152
  half8 a = *(const half8*)(pc + i8);
  half8 b = *(const half8*)(pc + STRIDE + i8);
  half8 c = *(const half8*)(pc + 2 * STRIDE + i8);
  half8 d = *(const half8*)(pc + 3 * STRIDE + i8);
  float4 r0, r1;
  r0.x = (float)a[0] + (float)b[0] + (float)c[0] + (float)d[0];
  r0.y = (float)a[1] + (float)b[1] + (float)c[1] + (float)d[1];
  r0.z = (float)a[2] + (float)b[2] + (float)c[2] + (float)d[2];
  r0.w = (float)a[3] + (float)b[3] + (float)c[3] + (float)d[3];
  r1.x = (float)a[4] + (float)b[4] + (float)c[4] + (float)d[4];
  r1.y = (float)a[5] + (float)b[5] + (float)c[5] + (float)d[5];
  r1.z = (float)a[6] + (float)b[6] + (float)c[6] + (float)d[6];
  r1.w = (float)a[7] + (float)b[7] + (float)c[7] + (float)d[7];
  *(float4*)(outc + i8) = r0;
  *(float4*)(outc + i8 + 4) = r1;
}

extern "C" void kernel_launch(void* const* d_in, const int* in_sizes, int n_in,
                              void* d_out, int out_size, void* d_ws, size_t ws_size,
                              hipStream_t stream) {
  const float* mbank = (const float*)d_in[0];  // (8,4096,256) f32
  const float* src   = (const float*)d_in[1];  // (8,1024,256) f32
  const int*   mask  = (const int*)d_in[2];    // (8,4096) bool->int
  const float* W     = (const float*)d_in[3];  // (256,256) f32

  float* out_c = (float*)d_out;                         // 2,097,152 f32
  float* out_align = out_c + (size_t)NBATCH * NT * ND;  // 33,554,432 f32

  // ws layout (total 24 MB):
  //   [0, 4 MB)        q16   : 8192x256 fp16                (K1 -> K2,K4)
  //   [4 MB, +512 KB)  pstats: 8192x8x2 f32                 (K2 -> K3)
  //   [5 MB, +32 KB)   sm    : 8192 f32
  //   [5.25 MB,+32 KB) slinv : 8192 f32
  //   [8 MB, 24 MB)    pc    : 4 x 2M fp16 split-K partials (K4 -> K5)
  char* ws = (char*)d_ws;
  f16* q16      = (f16*)ws;
  float* pstats = (float*)(ws + (4 << 20));
  float* sm     = (float*)(ws + (5 << 20));
  float* slinv  = (float*)(ws + (5 << 20) + (256 << 10));
  f16* pc       = (f16*)(ws + (8 << 20));

  hipLaunchKernelGGL(k_qproj, dim3(128), dim3(256), 0, stream, src, W, q16);
  hipLaunchKernelGGL(k_fstats, dim3(512), dim3(256), 0, stream,
                     mbank, q16, mask, pstats);
  hipLaunchKernelGGL(k_stats, dim3(32), dim3(256), 0, stream, pstats, sm, slinv);
  hipLaunchKernelGGL(k_pvfused, dim3(1024), dim3(256), 0, stream,
                     mbank, q16, mask, sm, slinv, out_align, pc);
  hipLaunchKernelGGL(k_csum, dim3(1024), dim3(256), 0, stream, pc, out_c);
}